// Round 4
// baseline (27969.617 us; speedup 1.0000x reference)
//
#include <hip/hip_runtime.h>
#include <math.h>

#define B 4
#define C 200
#define H 128
#define W 128
#define N 16384   // H*W
#define K 256
#define ITERS 5
#define FACT 1.25f   // COMPACTNESS / S = 10 / 8

// workspace layout (floats)
#define OFF_A2    0
#define OFF_CS    (OFF_A2 + B*N)            // 65536
#define OFF_CSPAT (OFF_CS + B*K*C)          // 270336
#define OFF_B2    (OFF_CSPAT + B*K*2)       // 272384
#define OFF_SACC  (OFF_B2 + B*K)            // 273408
#define OFF_MACC  (OFF_SACC + B*K*C)        // 478208
#define OFF_SPACC (OFF_MACC + B*K)          // 479232

// ---------------------------------------------------------------------------
// init: centers_spectral[b,k,c] = x[0,c,seed_n(k)]; centers_spatial = grid
__global__ void k_init(const float* __restrict__ x, float* __restrict__ cs,
                       float* __restrict__ cspat) {
  int k = blockIdx.x, c = threadIdx.x;
  int i = k >> 4, j = k & 15;
  int sn = (4 + 8*i)*W + (4 + 8*j);
  if (c < C) {
    float v = x[(size_t)c*N + sn];
    for (int b = 0; b < B; ++b) cs[((size_t)(b*K + k))*C + c] = v;
  }
  if (c == 0) {
    for (int b = 0; b < B; ++b) {
      cspat[(b*K + k)*2 + 0] = (float)(4 + 8*i);
      cspat[(b*K + k)*2 + 1] = (float)(4 + 8*j);
    }
  }
}

// a2[b,n] = sum_c x[b,c,n]^2  (iteration-invariant)
__global__ void k_a2(const float* __restrict__ x, float* __restrict__ a2) {
  int b = blockIdx.x >> 6;
  int n = ((blockIdx.x & 63) << 8) + threadIdx.x;
  const float* xp = x + (size_t)b*C*N + n;
  float s = 0.f;
  #pragma unroll 8
  for (int c = 0; c < C; ++c) { float v = xp[(size_t)c*N]; s += v*v; }
  a2[b*N + n] = s;
}

// b2[b,k] = sum_c cs[b,k,c]^2
__global__ void k_b2(const float* __restrict__ cs, float* __restrict__ b2) {
  int bk = blockIdx.x;
  const float* p = cs + (size_t)bk*C;
  float s = 0.f;
  for (int c = threadIdx.x; c < C; c += 64) { float v = p[c]; s += v*v; }
  for (int off = 32; off > 0; off >>= 1) s += __shfl_down(s, off);
  if (threadIdx.x == 0) b2[bk] = s;
}

// ---------------------------------------------------------------------------
// assignment: D = cdist_spectral + 1.25*cdist_spatial; Q = softmax(-D)
// block = 64 pixels of one batch; 256 threads = 8 kgroups x 32 pix; 2 pix/thread
#define CC 40
__global__ __launch_bounds__(256, 2) void k_assign(
    const float* __restrict__ x, const float* __restrict__ cs,
    const float* __restrict__ cspat, const float* __restrict__ b2,
    const float* __restrict__ a2, float* __restrict__ Q) {
  __shared__ float cs_lds[K*CC];    // [k][40]
  __shared__ float x_lds[64*44];    // [p][44] padded
  __shared__ float b2s[K], cys[K], cxs[K];
  __shared__ float red[2*8*64];

  int b  = blockIdx.x >> 8;
  int n0 = (blockIdx.x & 255) << 6;
  int tid = threadIdx.x;
  int kg = tid >> 5, pix = tid & 31;

  b2s[tid] = b2[b*K + tid];
  cys[tid] = cspat[(b*K + tid)*2 + 0];
  cxs[tid] = cspat[(b*K + tid)*2 + 1];

  float acc0[32], acc1[32];
  #pragma unroll
  for (int kq = 0; kq < 32; ++kq) { acc0[kq] = 0.f; acc1[kq] = 0.f; }

  const float* xb  = x  + (size_t)b*C*N;
  const float* csb = cs + (size_t)b*K*C;

  for (int t = 0; t < 5; ++t) {
    int cc0 = t * CC;
    __syncthreads();   // protect LDS from previous chunk's readers (also covers b2s writes)
    {  // cs chunk: thread loads row k = tid
      const float* src = csb + (size_t)tid*C + cc0;
      float* dst = &cs_lds[tid*CC];
      #pragma unroll
      for (int m = 0; m < 10; ++m)
        *(float4*)&dst[m*4] = *(const float4*)&src[m*4];
    }
    #pragma unroll
    for (int pass = 0; pass < 10; ++pass) {  // x chunk [64 pix][40 c]
      int idx = pass*256 + tid;
      int p = idx & 63, ci = idx >> 6;
      x_lds[p*44 + ci] = xb[(size_t)(cc0 + ci)*N + n0 + p];
    }
    __syncthreads();
    #pragma unroll
    for (int cc4 = 0; cc4 < 10; ++cc4) {
      float4 xa = *(const float4*)&x_lds[pix*44 + cc4*4];
      float4 xc = *(const float4*)&x_lds[(pix+32)*44 + cc4*4];
      #pragma unroll
      for (int kq = 0; kq < 32; ++kq) {
        float4 cv = *(const float4*)&cs_lds[(kg*32 + kq)*CC + cc4*4];
        acc0[kq] += xa.x*cv.x + xa.y*cv.y + xa.z*cv.z + xa.w*cv.w;
        acc1[kq] += xc.x*cv.x + xc.y*cv.y + xc.z*cv.z + xc.w*cv.w;
      }
    }
  }

  int p0 = pix, p1 = pix + 32;
  float a20 = a2[b*N + n0 + p0];
  float a21 = a2[b*N + n0 + p1];
  float py0 = (float)((n0 + p0) >> 7), px0 = (float)((n0 + p0) & 127);
  float py1 = (float)((n0 + p1) >> 7), px1 = (float)((n0 + p1) & 127);

  float mn0 = 1e30f, mn1 = 1e30f;
  #pragma unroll
  for (int kq = 0; kq < 32; ++kq) {
    int k = kg*32 + kq;
    float b2v = b2s[k], cy = cys[k], cx = cxs[k];
    float dy0 = py0 - cy, dx0 = px0 - cx;
    float dy1 = py1 - cy, dx1 = px1 - cx;
    float d0 = sqrtf(fmaxf(a20 + b2v - 2.f*acc0[kq], 1e-12f))
             + FACT*sqrtf(fmaxf(dy0*dy0 + dx0*dx0, 1e-12f));
    float d1 = sqrtf(fmaxf(a21 + b2v - 2.f*acc1[kq], 1e-12f))
             + FACT*sqrtf(fmaxf(dy1*dy1 + dx1*dx1, 1e-12f));
    acc0[kq] = d0; acc1[kq] = d1;
    mn0 = fminf(mn0, d0); mn1 = fminf(mn1, d1);
  }
  red[kg*64 + p0] = mn0;
  red[kg*64 + p1] = mn1;
  __syncthreads();
  #pragma unroll
  for (int g = 0; g < 8; ++g) {
    mn0 = fminf(mn0, red[g*64 + p0]);
    mn1 = fminf(mn1, red[g*64 + p1]);
  }
  float s0 = 0.f, s1 = 0.f;
  #pragma unroll
  for (int kq = 0; kq < 32; ++kq) {
    float e0 = __expf(mn0 - acc0[kq]);
    float e1 = __expf(mn1 - acc1[kq]);
    acc0[kq] = e0; acc1[kq] = e1;
    s0 += e0; s1 += e1;
  }
  red[512 + kg*64 + p0] = s0;
  red[512 + kg*64 + p1] = s1;
  __syncthreads();
  s0 = 0.f; s1 = 0.f;
  #pragma unroll
  for (int g = 0; g < 8; ++g) {
    s0 += red[512 + g*64 + p0];
    s1 += red[512 + g*64 + p1];
  }
  float inv0 = 1.f / s0, inv1 = 1.f / s1;
  float* q0 = Q + ((size_t)(b*N + n0 + p0))*K + kg*32;
  float* q1 = Q + ((size_t)(b*N + n0 + p1))*K + kg*32;
  #pragma unroll
  for (int m = 0; m < 8; ++m) {
    float4 v0 = make_float4(acc0[m*4]*inv0, acc0[m*4+1]*inv0,
                            acc0[m*4+2]*inv0, acc0[m*4+3]*inv0);
    float4 v1 = make_float4(acc1[m*4]*inv1, acc1[m*4+1]*inv1,
                            acc1[m*4+2]*inv1, acc1[m*4+3]*inv1);
    *(float4*)&q0[m*4] = v0;
    *(float4*)&q1[m*4] = v1;
  }
}

// ---------------------------------------------------------------------------
// update: sacc[b,k,c] += sum_n Q[b,n,k]*x[b,c,n]; mass/spatial on ct==0
// grid = B * 4 ctiles * 32 ntiles; 256 threads, thread owns k=tid, 50 c's
__global__ __launch_bounds__(256, 2) void k_update(
    const float* __restrict__ x, const float* __restrict__ Q,
    float* __restrict__ sacc, float* __restrict__ macc,
    float* __restrict__ spacc) {
  __shared__ float q_lds[32*256];   // [n][k]
  __shared__ float x_lds[32*52];    // [n][c] padded
  int bid = blockIdx.x;
  int b = bid >> 7;
  int rest = bid & 127;
  int ct = rest >> 5;   // 0..3
  int nt = rest & 31;   // 0..31
  int tid = threadIdx.x;
  int c0 = ct * 50;

  float acc[50];
  #pragma unroll
  for (int c = 0; c < 50; ++c) acc[c] = 0.f;
  float mass = 0.f, sy = 0.f, sx = 0.f;

  const float*  xb = x + (size_t)b*C*N + (size_t)c0*N;
  const float4* Q4 = (const float4*)(Q + (size_t)b*N*K);

  for (int ch = 0; ch < 16; ++ch) {
    int nb = nt*512 + ch*32;
    __syncthreads();
    #pragma unroll
    for (int pass = 0; pass < 8; ++pass) {  // Q chunk [32n][256k]
      int idx = pass*256 + tid;
      int nr = idx >> 6, kc4 = idx & 63;
      *(float4*)&q_lds[nr*256 + kc4*4] = Q4[(size_t)(nb + nr)*64 + kc4];
    }
    #pragma unroll
    for (int pass = 0; pass < 7; ++pass) {  // x chunk [50c][32n] -> [n][c]
      int idx = pass*256 + tid;
      if (idx < 1600) {
        int ci = idx >> 5, nn = idx & 31;
        x_lds[nn*52 + ci] = xb[(size_t)ci*N + nb + nn];
      }
    }
    __syncthreads();
    float py  = (float)(nb >> 7);        // constant within 32-n chunk
    float pxb = (float)(nb & 127);
    for (int nn = 0; nn < 32; ++nn) {
      float q = q_lds[nn*256 + tid];
      if (ct == 0) {
        mass += q;
        sy += q * py;
        sx += q * (pxb + (float)nn);
      }
      const float* xr = &x_lds[nn*52];
      #pragma unroll
      for (int c4 = 0; c4 < 12; ++c4) {
        float4 xv = *(const float4*)&xr[c4*4];
        acc[c4*4+0] += q*xv.x; acc[c4*4+1] += q*xv.y;
        acc[c4*4+2] += q*xv.z; acc[c4*4+3] += q*xv.w;
      }
      acc[48] += q*xr[48];
      acc[49] += q*xr[49];
    }
  }
  float* sp = sacc + ((size_t)(b*K + tid))*C + c0;
  #pragma unroll
  for (int c = 0; c < 50; ++c) atomicAdd(&sp[c], acc[c]);
  if (ct == 0) {
    atomicAdd(&macc[b*K + tid], mass);
    atomicAdd(&spacc[(b*K + tid)*2 + 0], sy);
    atomicAdd(&spacc[(b*K + tid)*2 + 1], sx);
  }
}

// finalize: divide by mass; write centers (and to d_out tail on last iter)
__global__ void k_final(const float* __restrict__ sacc, const float* __restrict__ macc,
                        const float* __restrict__ spacc, float* __restrict__ cs,
                        float* __restrict__ cspat, float* __restrict__ outc, int last) {
  int bk = blockIdx.x;
  int c = threadIdx.x;
  float inv = 1.f / (macc[bk] + 1e-6f);
  if (c < C) {
    float v = sacc[(size_t)bk*C + c] * inv;
    cs[(size_t)bk*C + c] = v;
    if (last) outc[(size_t)bk*C + c] = v;
  } else if (c == C) {
    cspat[bk*2 + 0] = spacc[bk*2 + 0] * inv;
  } else if (c == C + 1) {
    cspat[bk*2 + 1] = spacc[bk*2 + 1] * inv;
  }
}

extern "C" void kernel_launch(void* const* d_in, const int* in_sizes, int n_in,
                              void* d_out, int out_size, void* d_ws, size_t ws_size,
                              hipStream_t stream) {
  const float* x = (const float*)d_in[0];
  float* out = (float*)d_out;
  float* ws  = (float*)d_ws;
  float* a2    = ws + OFF_A2;
  float* cs    = ws + OFF_CS;
  float* cspat = ws + OFF_CSPAT;
  float* b2    = ws + OFF_B2;
  float* sacc  = ws + OFF_SACC;
  float* macc  = ws + OFF_MACC;
  float* spacc = ws + OFF_SPACC;
  float* outc  = out + (size_t)B*N*K;

  hipLaunchKernelGGL(k_init, dim3(K), dim3(256), 0, stream, x, cs, cspat);
  hipLaunchKernelGGL(k_a2, dim3(B*64), dim3(256), 0, stream, x, a2);
  for (int it = 0; it < ITERS; ++it) {
    hipLaunchKernelGGL(k_b2, dim3(B*K), dim3(64), 0, stream, cs, b2);
    hipLaunchKernelGGL(k_assign, dim3(B*256), dim3(256), 0, stream,
                       x, cs, cspat, b2, a2, out);
    hipMemsetAsync(sacc, 0, (size_t)(B*K*C + B*K + B*K*2)*sizeof(float), stream);
    hipLaunchKernelGGL(k_update, dim3(512), dim3(256), 0, stream,
                       x, out, sacc, macc, spacc);
    hipLaunchKernelGGL(k_final, dim3(B*K), dim3(256), 0, stream,
                       sacc, macc, spacc, cs, cspat, outc, (it == ITERS-1) ? 1 : 0);
  }
}

// Round 5
// 5521.008 us; speedup vs baseline: 5.0660x; 5.0660x over previous
//
#include <hip/hip_runtime.h>
#include <math.h>

#define B 4
#define C 200
#define H 128
#define W 128
#define N 16384   // H*W
#define K 256
#define ITERS 5
#define FACT 1.25f   // COMPACTNESS / S = 10 / 8

// workspace layout (floats)
#define OFF_A2    0
#define OFF_CS    (OFF_A2 + B*N)            // 65536
#define OFF_CSPAT (OFF_CS + B*K*C)          // 270336
#define OFF_B2    (OFF_CSPAT + B*K*2)       // 272384
#define OFF_SACC  (OFF_B2 + B*K)            // 273408
#define OFF_MACC  (OFF_SACC + B*K*C)        // 478208
#define OFF_SPACC (OFF_MACC + B*K)          // 479232

// ---------------------------------------------------------------------------
// init: centers_spectral[b,k,c] = x[0,c,seed_n(k)]; centers_spatial = grid
__global__ void k_init(const float* __restrict__ x, float* __restrict__ cs,
                       float* __restrict__ cspat) {
  int k = blockIdx.x, c = threadIdx.x;
  int i = k >> 4, j = k & 15;
  int sn = (4 + 8*i)*W + (4 + 8*j);
  if (c < C) {
    float v = x[(size_t)c*N + sn];
    for (int b = 0; b < B; ++b) cs[((size_t)(b*K + k))*C + c] = v;
  }
  if (c == 0) {
    for (int b = 0; b < B; ++b) {
      cspat[(b*K + k)*2 + 0] = (float)(4 + 8*i);
      cspat[(b*K + k)*2 + 1] = (float)(4 + 8*j);
    }
  }
}

// a2[b,n] = sum_c x[b,c,n]^2  (iteration-invariant)
__global__ void k_a2(const float* __restrict__ x, float* __restrict__ a2) {
  int b = blockIdx.x >> 6;
  int n = ((blockIdx.x & 63) << 8) + threadIdx.x;
  const float* xp = x + (size_t)b*C*N + n;
  float s = 0.f;
  #pragma unroll 8
  for (int c = 0; c < C; ++c) { float v = xp[(size_t)c*N]; s += v*v; }
  a2[b*N + n] = s;
}

// b2[b,k] = sum_c cs[b,k,c]^2
__global__ void k_b2(const float* __restrict__ cs, float* __restrict__ b2) {
  int bk = blockIdx.x;
  const float* p = cs + (size_t)bk*C;
  float s = 0.f;
  for (int c = threadIdx.x; c < C; c += 64) { float v = p[c]; s += v*v; }
  for (int off = 32; off > 0; off >>= 1) s += __shfl_down(s, off);
  if (threadIdx.x == 0) b2[bk] = s;
}

// ---------------------------------------------------------------------------
// assignment v2: 512 threads = 8 kgroups(32k) x 64 pixels; 1 pixel/thread,
// acc[32] only. Wave == kgroup -> cs addresses wave-uniform (s_load path).
// x tile staged in LDS; cs read directly from global (L2-resident, 204KB/batch).
__global__ __launch_bounds__(512) void k_assign(
    const float* __restrict__ x, const float* __restrict__ cs,
    const float* __restrict__ cspat, const float* __restrict__ b2,
    const float* __restrict__ a2, float* __restrict__ Q) {
  __shared__ float x_lds[64*44];    // [pix][44] padded (40 used)
  __shared__ float b2s[K], cys[K], cxs[K];
  __shared__ float red[512];        // [kg][pix]

  int b   = blockIdx.x >> 8;          // 256 blocks per batch
  int n0  = (blockIdx.x & 255) << 6;  // 64 pixels per block
  int tid = threadIdx.x;
  int kg  = __builtin_amdgcn_readfirstlane(tid >> 6);  // wave-uniform 0..7
  int pix = tid & 63;

  if (tid < K) {
    b2s[tid] = b2[b*K + tid];
    cys[tid] = cspat[(b*K + tid)*2 + 0];
    cxs[tid] = cspat[(b*K + tid)*2 + 1];
  }

  float acc[32];
  #pragma unroll
  for (int kq = 0; kq < 32; ++kq) acc[kq] = 0.f;

  const float* xb  = x  + (size_t)b*C*N;
  const float* csb = cs + (size_t)b*K*C + (size_t)kg*32*C;  // uniform per wave

  for (int t = 0; t < 5; ++t) {
    int cc0 = t * 40;
    __syncthreads();   // protect x_lds from previous chunk's readers (covers b2s too)
    #pragma unroll
    for (int pass = 0; pass < 5; ++pass) {   // stage x [64 pix][40 c]
      int idx = pass*512 + tid;
      int p = idx & 63, ci = idx >> 6;
      x_lds[p*44 + ci] = xb[(size_t)(cc0 + ci)*N + n0 + p];
    }
    __syncthreads();
    #pragma unroll
    for (int cc4 = 0; cc4 < 10; ++cc4) {
      float4 xa = *(const float4*)&x_lds[pix*44 + cc4*4];
      #pragma unroll
      for (int kq = 0; kq < 32; ++kq) {
        const float* cp = csb + kq*C + cc0 + cc4*4;  // wave-uniform address
        float a = acc[kq];
        a = fmaf(xa.x, cp[0], a);
        a = fmaf(xa.y, cp[1], a);
        a = fmaf(xa.z, cp[2], a);
        a = fmaf(xa.w, cp[3], a);
        acc[kq] = a;
      }
    }
  }

  // ---- distances + softmax over K (cross-kgroup via LDS) ----
  int n = n0 + pix;
  float a2v = a2[b*N + n];
  float py = (float)(n >> 7), px = (float)(n & 127);

  float mn = 1e30f;
  #pragma unroll
  for (int kq = 0; kq < 32; ++kq) {
    int k = kg*32 + kq;
    float b2v = b2s[k];           // same addr across wave -> LDS broadcast
    float dy = py - cys[k], dx = px - cxs[k];
    float d = sqrtf(fmaxf(a2v + b2v - 2.f*acc[kq], 1e-12f))
            + FACT*sqrtf(fmaxf(dy*dy + dx*dx, 1e-12f));
    acc[kq] = d;
    mn = fminf(mn, d);
  }
  red[kg*64 + pix] = mn;
  __syncthreads();
  #pragma unroll
  for (int g = 0; g < 8; ++g) mn = fminf(mn, red[g*64 + pix]);

  float s = 0.f;
  #pragma unroll
  for (int kq = 0; kq < 32; ++kq) {
    float e = __expf(mn - acc[kq]);
    acc[kq] = e;
    s += e;
  }
  __syncthreads();   // all reads of red (min phase) done before overwrite
  red[kg*64 + pix] = s;
  __syncthreads();
  s = 0.f;
  #pragma unroll
  for (int g = 0; g < 8; ++g) s += red[g*64 + pix];
  float inv = 1.f / s;

  float* q = Q + ((size_t)(b*N + n))*K + kg*32;
  #pragma unroll
  for (int m = 0; m < 8; ++m) {
    float4 v = make_float4(acc[m*4]*inv, acc[m*4+1]*inv,
                           acc[m*4+2]*inv, acc[m*4+3]*inv);
    *(float4*)&q[m*4] = v;
  }
}

// ---------------------------------------------------------------------------
// update: sacc[b,k,c] += sum_n Q[b,n,k]*x[b,c,n]; mass/spatial on ct==0
// grid = B * 4 ctiles * 32 ntiles; 256 threads, thread owns k=tid, 50 c's
__global__ __launch_bounds__(256, 2) void k_update(
    const float* __restrict__ x, const float* __restrict__ Q,
    float* __restrict__ sacc, float* __restrict__ macc,
    float* __restrict__ spacc) {
  __shared__ float q_lds[32*256];   // [n][k]
  __shared__ float x_lds[32*52];    // [n][c] padded
  int bid = blockIdx.x;
  int b = bid >> 7;
  int rest = bid & 127;
  int ct = rest >> 5;   // 0..3
  int nt = rest & 31;   // 0..31
  int tid = threadIdx.x;
  int c0 = ct * 50;

  float acc[50];
  #pragma unroll
  for (int c = 0; c < 50; ++c) acc[c] = 0.f;
  float mass = 0.f, sy = 0.f, sx = 0.f;

  const float*  xb = x + (size_t)b*C*N + (size_t)c0*N;
  const float4* Q4 = (const float4*)(Q + (size_t)b*N*K);

  for (int ch = 0; ch < 16; ++ch) {
    int nb = nt*512 + ch*32;
    __syncthreads();
    #pragma unroll
    for (int pass = 0; pass < 8; ++pass) {  // Q chunk [32n][256k]
      int idx = pass*256 + tid;
      int nr = idx >> 6, kc4 = idx & 63;
      *(float4*)&q_lds[nr*256 + kc4*4] = Q4[(size_t)(nb + nr)*64 + kc4];
    }
    #pragma unroll
    for (int pass = 0; pass < 7; ++pass) {  // x chunk [50c][32n] -> [n][c]
      int idx = pass*256 + tid;
      if (idx < 1600) {
        int ci = idx >> 5, nn = idx & 31;
        x_lds[nn*52 + ci] = xb[(size_t)ci*N + nb + nn];
      }
    }
    __syncthreads();
    float py  = (float)(nb >> 7);        // constant within 32-n chunk
    float pxb = (float)(nb & 127);
    for (int nn = 0; nn < 32; ++nn) {
      float q = q_lds[nn*256 + tid];
      if (ct == 0) {
        mass += q;
        sy += q * py;
        sx += q * (pxb + (float)nn);
      }
      const float* xr = &x_lds[nn*52];
      #pragma unroll
      for (int c4 = 0; c4 < 12; ++c4) {
        float4 xv = *(const float4*)&xr[c4*4];
        acc[c4*4+0] += q*xv.x; acc[c4*4+1] += q*xv.y;
        acc[c4*4+2] += q*xv.z; acc[c4*4+3] += q*xv.w;
      }
      acc[48] += q*xr[48];
      acc[49] += q*xr[49];
    }
  }
  float* sp = sacc + ((size_t)(b*K + tid))*C + c0;
  #pragma unroll
  for (int c = 0; c < 50; ++c) atomicAdd(&sp[c], acc[c]);
  if (ct == 0) {
    atomicAdd(&macc[b*K + tid], mass);
    atomicAdd(&spacc[(b*K + tid)*2 + 0], sy);
    atomicAdd(&spacc[(b*K + tid)*2 + 1], sx);
  }
}

// finalize: divide by mass; write centers (and to d_out tail on last iter)
__global__ void k_final(const float* __restrict__ sacc, const float* __restrict__ macc,
                        const float* __restrict__ spacc, float* __restrict__ cs,
                        float* __restrict__ cspat, float* __restrict__ outc, int last) {
  int bk = blockIdx.x;
  int c = threadIdx.x;
  float inv = 1.f / (macc[bk] + 1e-6f);
  if (c < C) {
    float v = sacc[(size_t)bk*C + c] * inv;
    cs[(size_t)bk*C + c] = v;
    if (last) outc[(size_t)bk*C + c] = v;
  } else if (c == C) {
    cspat[bk*2 + 0] = spacc[bk*2 + 0] * inv;
  } else if (c == C + 1) {
    cspat[bk*2 + 1] = spacc[bk*2 + 1] * inv;
  }
}

extern "C" void kernel_launch(void* const* d_in, const int* in_sizes, int n_in,
                              void* d_out, int out_size, void* d_ws, size_t ws_size,
                              hipStream_t stream) {
  const float* x = (const float*)d_in[0];
  float* out = (float*)d_out;
  float* ws  = (float*)d_ws;
  float* a2    = ws + OFF_A2;
  float* cs    = ws + OFF_CS;
  float* cspat = ws + OFF_CSPAT;
  float* b2    = ws + OFF_B2;
  float* sacc  = ws + OFF_SACC;
  float* macc  = ws + OFF_MACC;
  float* spacc = ws + OFF_SPACC;
  float* outc  = out + (size_t)B*N*K;

  hipLaunchKernelGGL(k_init, dim3(K), dim3(256), 0, stream, x, cs, cspat);
  hipLaunchKernelGGL(k_a2, dim3(B*64), dim3(256), 0, stream, x, a2);
  for (int it = 0; it < ITERS; ++it) {
    hipLaunchKernelGGL(k_b2, dim3(B*K), dim3(64), 0, stream, cs, b2);
    hipLaunchKernelGGL(k_assign, dim3(B*256), dim3(512), 0, stream,
                       x, cs, cspat, b2, a2, out);
    hipMemsetAsync(sacc, 0, (size_t)(B*K*C + B*K + B*K*2)*sizeof(float), stream);
    hipLaunchKernelGGL(k_update, dim3(512), dim3(256), 0, stream,
                       x, out, sacc, macc, spacc);
    hipLaunchKernelGGL(k_final, dim3(B*K), dim3(256), 0, stream,
                       sacc, macc, spacc, cs, cspat, outc, (it == ITERS-1) ? 1 : 0);
  }
}